// Round 12
// baseline (123.481 us; speedup 1.0000x reference)
//
#include <hip/hip_runtime.h>

typedef unsigned short u16;
typedef __attribute__((ext_vector_type(4))) float f32x4;
typedef __attribute__((ext_vector_type(8))) short bf16x8;

#define MFMA16(a,b,c) __builtin_amdgcn_mfma_f32_16x16x32_bf16((a),(b),(c),0,0,0)

__device__ inline u16 f2bf(float f){
  union { float f; unsigned u; } v; v.f = f;
  unsigned r = v.u + 0x7FFFu + ((v.u >> 16) & 1u);
  return (u16)(r >> 16);
}
__device__ inline u16 f2bf_fast(float f){
  union { float f; unsigned u; } v; v.f = f;
  return (u16)((v.u + 0x8000u) >> 16);
}
// pack two f32 -> two bf16 in one u32 (round-half-away)
__device__ inline unsigned pk2bf(float x, float y){
  union { float f; unsigned u; } a, b; a.f=x; b.f=y;
  return ((a.u + 0x8000u)>>16) | ((b.u + 0x8000u) & 0xFFFF0000u);
}

typedef const __attribute__((address_space(1))) unsigned int* gas_ptr;
typedef __attribute__((address_space(3))) unsigned int* las_ptr;
__device__ inline void gload_lds16(const u16* g, u16* l){
  __builtin_amdgcn_global_load_lds((gas_ptr)(const void*)g, (las_ptr)(void*)l, 16, 0, 0);
}

// ---------------- W (K x N) fp32 -> Wt (N x K) bf16, 4 weights ----------------
struct TwbArgs { const float* W[4]; u16* Wt[4]; };
__global__ void k_twb4(TwbArgs a){
  __shared__ u16 t[32][33];
  const float* W = a.W[blockIdx.z];
  u16* Wt = a.Wt[blockIdx.z];
  int kb = blockIdx.x*32, nb = blockIdx.y*32;
  int tx = threadIdx.x, ty = threadIdx.y;
  #pragma unroll
  for (int i=0;i<32;i+=8)
    t[ty+i][tx] = f2bf(W[(size_t)(kb+ty+i)*1024 + nb+tx]);
  __syncthreads();
  #pragma unroll
  for (int i=0;i<32;i+=8)
    Wt[(size_t)(nb+ty+i)*1024 + kb+tx] = t[tx][ty+i];
}

// ---------------- V (B*T, D) bf16 -> VT (B,H,DH,T) bf16 ----------------
__global__ void k_tv(const u16* __restrict__ V, u16* __restrict__ VT){
  __shared__ u16 t[32][33];
  int tb = blockIdx.x*32;
  int db = blockIdx.y*32;
  int bh = blockIdx.z;
  int b = bh>>4, h = bh&15;
  int tx = threadIdx.x, ty = threadIdx.y;
  #pragma unroll
  for (int i=0;i<32;i+=8)
    t[ty+i][tx] = V[(size_t)(b*2048 + tb+ty+i)*1024 + h*64 + db+tx];
  __syncthreads();
  #pragma unroll
  for (int i=0;i<32;i+=8)
    VT[(size_t)(bh*64 + db+ty+i)*2048 + tb+tx] = t[tx][ty+i];
}

// ---------------- QKV projections, 128x128 tile, FUSED fp32->bf16 on A ----------------
// A staged as fp32 (32KB, XOR-swizzled via pre-swizzled global source), converted
// to bf16 at frag-read (2x ds_read_b128 + 4 pack per frag). B staging/reads now
// XOR-swizzled too (kills the 16-way row-column conflict). Kills the k_cvt3 pass.
struct GemmArgs3 { const float* A[3]; const u16* Bt[3]; const float* bias[3]; u16* C[3]; };
__global__ __launch_bounds__(256) void k_gemm3(GemmArgs3 g){
  const int N=1024, K=1024;
  int flat = blockIdx.x + (blockIdx.y<<5) + (blockIdx.z<<8);
  int swz = (flat&7)*96 + (flat>>3);
  int by = swz & 7, bx = (swz>>3) & 31, bz = swz >> 8;
  const float* A = g.A[bz]; const u16* Bt = g.Bt[bz];
  const float* bias = g.bias[bz]; u16* C = g.C[bz];
  __shared__ __attribute__((aligned(16))) float As[128*64];   // fp32 tile, 32KB
  __shared__ __attribute__((aligned(16))) u16   Bs[128*64];   // bf16 tile, 16KB
  const int tid  = threadIdx.x;
  const int wave = tid>>6, lane = tid&63;
  const int lo = lane&15, hi = lane>>4;
  const int lo7 = lo&7;
  const int row0 = bx*128, col0 = by*128;
  const int wm = (wave>>1)*64, wn = (wave&1)*64;
  f32x4 acc[4][4];
  #pragma unroll
  for (int i=0;i<4;i++)
    #pragma unroll
    for (int j=0;j<4;j++) acc[i][j] = (f32x4){0.f,0.f,0.f,0.f};

  for (int k0=0; k0<K; k0+=64){
    // A: 2048 granules of 16B (16/row); linear LDS dest, pre-swizzled source col
    #pragma unroll
    for (int r=0;r<8;r++){
      int ga = r*256 + tid;
      int sr = ga>>4, lg = (ga&15) ^ (sr&7);
      gload_lds16((const u16*)(A + (size_t)(row0+sr)*K + k0 + lg*4), (u16*)(As + ga*4));
    }
    // B: 1024 granules of 16B (8/row), same swizzle scheme
    #pragma unroll
    for (int r=0;r<4;r++){
      int c = r*256 + tid;
      int sr = c>>3, lg = (c&7) ^ (sr&7);
      gload_lds16(Bt + (size_t)(col0 + sr)*K + k0 + lg*8, Bs + c*8);
    }
    __syncthreads();
    __builtin_amdgcn_s_setprio(1);
    #pragma unroll
    for (int ks=0;ks<2;ks++){
      bf16x8 af[4], bfr[4];
      #pragma unroll
      for (int mf=0;mf<4;mf++){
        const float* Arow = As + (wm+mf*16+lo)*64;
        int q0 = ks*8 + hi*2;                       // logical 16B granule (4 f32)
        f32x4 a0 = *(const f32x4*)(Arow + ((q0  )^lo7)*4);
        f32x4 a1 = *(const f32x4*)(Arow + ((q0+1)^lo7)*4);
        union { unsigned u[4]; bf16x8 v; } pk;
        pk.u[0] = pk2bf(a0[0], a0[1]);
        pk.u[1] = pk2bf(a0[2], a0[3]);
        pk.u[2] = pk2bf(a1[0], a1[1]);
        pk.u[3] = pk2bf(a1[2], a1[3]);
        af[mf] = pk.v;
      }
      #pragma unroll
      for (int nf=0;nf<4;nf++)
        bfr[nf] = *(const bf16x8*)(Bs + (wn+nf*16+lo)*64 + ((ks*4+hi)^lo7)*8);
      #pragma unroll
      for (int mf=0;mf<4;mf++)
        #pragma unroll
        for (int nf=0;nf<4;nf++)
          acc[mf][nf] = MFMA16(af[mf], bfr[nf], acc[mf][nf]);
    }
    __builtin_amdgcn_s_setprio(0);
    __syncthreads();
  }
  #pragma unroll
  for (int mf=0;mf<4;mf++){
    #pragma unroll
    for (int nf=0;nf<4;nf++){
      int r0 = row0 + wm + mf*16 + hi*4;
      int c0 = col0 + wn + nf*16 + lo;
      float bv = bias[c0];
      #pragma unroll
      for (int r=0;r<4;r++)
        C[(size_t)(r0+r)*N + c0] = f2bf(acc[mf][nf][r] + bv);
    }
  }
}

// ---------------- O projection: 64x128 tiles, 512 blocks (2/CU) ----------------
__global__ __launch_bounds__(256) void k_gemmO(const u16* __restrict__ A, const u16* __restrict__ Bt,
                                               const float* __restrict__ bias, float* __restrict__ C){
  const int N=1024, K=1024;
  int f = blockIdx.x;
  int xcd = f & 7, idx = f >> 3;
  int bx = xcd*8 + (idx>>3), by = idx & 7;   // row-stripe per XCD
  __shared__ __attribute__((aligned(16))) u16 As[64*64];
  __shared__ __attribute__((aligned(16))) u16 Bs[128*64];
  const int tid  = threadIdx.x;
  const int wave = tid>>6, lane = tid&63;
  const int lo = lane&15, hi = lane>>4;
  const int row0 = bx*64, col0 = by*128;
  const int wm = (wave>>1)*32, wn = (wave&1)*64;
  f32x4 acc[2][4];
  #pragma unroll
  for (int i=0;i<2;i++)
    #pragma unroll
    for (int j=0;j<4;j++) acc[i][j] = (f32x4){0.f,0.f,0.f,0.f};

  for (int k0=0; k0<K; k0+=64){
    #pragma unroll
    for (int r=0;r<2;r++){
      int c = r*256 + tid;
      gload_lds16(A + (size_t)(row0 + (c>>3))*K + k0 + (c&7)*8, As + c*8);
    }
    #pragma unroll
    for (int r=0;r<4;r++){
      int c = r*256 + tid;
      gload_lds16(Bt + (size_t)(col0 + (c>>3))*K + k0 + (c&7)*8, Bs + c*8);
    }
    __syncthreads();
    __builtin_amdgcn_s_setprio(1);
    #pragma unroll
    for (int ks=0;ks<2;ks++){
      bf16x8 af[2], bfr[4];
      #pragma unroll
      for (int mf=0;mf<2;mf++)
        af[mf] = *(const bf16x8*)(As + (wm+mf*16+lo)*64 + ks*32 + hi*8);
      #pragma unroll
      for (int nf=0;nf<4;nf++)
        bfr[nf] = *(const bf16x8*)(Bs + (wn+nf*16+lo)*64 + ks*32 + hi*8);
      #pragma unroll
      for (int mf=0;mf<2;mf++)
        #pragma unroll
        for (int nf=0;nf<4;nf++)
          acc[mf][nf] = MFMA16(af[mf], bfr[nf], acc[mf][nf]);
    }
    __builtin_amdgcn_s_setprio(0);
    __syncthreads();
  }
  #pragma unroll
  for (int mf=0;mf<2;mf++){
    #pragma unroll
    for (int nf=0;nf<4;nf++){
      int r0 = row0 + wm + mf*16 + hi*4;
      int c0 = col0 + wn + nf*16 + lo;
      float bv = bias[c0];
      #pragma unroll
      for (int r=0;r<4;r++)
        C[(size_t)(r0+r)*N + c0] = acc[mf][nf][r] + bv;
    }
  }
}

// ---------------- flash attention (causal), v10 (proven): 2x2 wave split ----------------
__global__ __launch_bounds__(256) void k_attn(
    const u16* __restrict__ Q, const u16* __restrict__ Kp,
    const u16* __restrict__ VT, u16* __restrict__ O)
{
  const int T=2048, D=1024;
  __shared__ __attribute__((aligned(16))) u16 Ks[2][64*64];
  __shared__ __attribute__((aligned(16))) u16 Vs[2][64*64];
  __shared__ __attribute__((aligned(16))) u16 Plds[4][16*64];
  int f = blockIdx.x + (blockIdx.y<<5);
  int xcd = f & 7, idx = f >> 3;
  const int bh = (xcd<<2) | (idx&3);
  const int qb = 31 - (idx>>2);
  const int b = bh>>4, h = bh&15;
  const int tid = threadIdx.x;
  const int wave = tid>>6, lane = tid&63;
  const int lo = lane&15, hi = lane>>4;
  const int wi = wave>>1, wj = wave&1;     // q-half, k-half
  const int lo7 = lo&7;
  const float NEG = -1e30f;
  const float sc = 0.125f * 1.44269504f;      // 1/sqrt(64) * log2(e)
  const float MC = 64.0f * sc;                // static shift
  const bf16x8 ones = {0x3F80,0x3F80,0x3F80,0x3F80,0x3F80,0x3F80,0x3F80,0x3F80};

  const int c0 = tid, c1 = 256 + tid;
  const int sr0 = c0>>3, sj0 = (c0&7)^(sr0&7);
  const int sr1 = c1>>3, sj1 = (c1&7)^(sr1&7);
  const u16* Kbase = Kp + (size_t)(b*T)*D + h*64;
  const u16* Vbase = VT + (size_t)(bh*64)*T;
  const size_t kOff0 = (size_t)sr0*D + sj0*8, kOff1 = (size_t)sr1*D + sj1*8;
  const size_t vOff0 = (size_t)sr0*T + sj0*8, vOff1 = (size_t)sr1*T + sj1*8;

  const int qrow0 = qb*64 + wi*32;
  bf16x8 qf[2][2];
  #pragma unroll
  for (int qnf=0;qnf<2;qnf++){
    const u16* Qr = Q + (size_t)(b*T + qrow0 + qnf*16 + lo)*D + h*64;
    qf[qnf][0] = *(const bf16x8*)(Qr + hi*8);
    qf[qnf][1] = *(const bf16x8*)(Qr + 32 + hi*8);
  }

  f32x4 o[2][4];
  #pragma unroll
  for (int i=0;i<2;i++)
    #pragma unroll
    for (int j=0;j<4;j++) o[i][j] = (f32x4){0.f,0.f,0.f,0.f};
  f32x4 lac[2];
  lac[0] = (f32x4){0.f,0.f,0.f,0.f};
  lac[1] = (f32x4){0.f,0.f,0.f,0.f};

  gload_lds16(Kbase + kOff0, &Ks[0][c0*8]);
  gload_lds16(Kbase + kOff1, &Ks[0][c1*8]);
  gload_lds16(Vbase + vOff0, &Vs[0][c0*8]);
  gload_lds16(Vbase + vOff1, &Vs[0][c1*8]);
  __syncthreads();

  u16* Pl = &Plds[wave][0];
  const int kcof0 = ((     hi) ^ lo7)*8;
  const int kcof1 = (( 4 + hi) ^ lo7)*8;
  const int vcof  = ((wj*4+hi) ^ lo7)*8;

  int cur = 0;
  for (int kb=0; kb<=qb; kb++){
    if (kb < qb){
      const u16* Kt = Kbase + (size_t)(kb+1)*64*D;
      const u16* Vt = Vbase + (kb+1)*64;
      gload_lds16(Kt + kOff0, &Ks[cur^1][c0*8]);
      gload_lds16(Kt + kOff1, &Ks[cur^1][c1*8]);
      gload_lds16(Vt + vOff0, &Vs[cur^1][c0*8]);
      gload_lds16(Vt + vOff1, &Vs[cur^1][c1*8]);
    }
    const u16* Kl = Ks[cur];
    const u16* Vl = Vs[cur];
    f32x4 s[2][2];
    __builtin_amdgcn_s_setprio(1);
    #pragma unroll
    for (int knf=0;knf<2;knf++){
      int krow = wj*32 + knf*16 + lo;
      bf16x8 kf0 = *(const bf16x8*)(Kl + krow*64 + kcof0);
      bf16x8 kf1 = *(const bf16x8*)(Kl + krow*64 + kcof1);
      #pragma unroll
      for (int qnf=0;qnf<2;qnf++){
        f32x4 z = (f32x4){0.f,0.f,0.f,0.f};
        z = MFMA16(kf0, qf[qnf][0], z);
        s[knf][qnf] = MFMA16(kf1, qf[qnf][1], z);
      }
    }
    __builtin_amdgcn_s_setprio(0);
    if (kb == qb){
      int ql = wi*32 + lo;
      #pragma unroll
      for (int knf=0;knf<2;knf++){
        int kl0 = wj*32 + knf*16 + 4*hi;
        #pragma unroll
        for (int qnf=0;qnf<2;qnf++){
          int qv = ql + qnf*16;
          #pragma unroll
          for (int r=0;r<4;r++)
            if (kl0 + r > qv) s[knf][qnf][r] = NEG;
        }
      }
    }
    #pragma unroll
    for (int knf=0;knf<2;knf++)
      #pragma unroll
      for (int qnf=0;qnf<2;qnf++){
        float p0 = __builtin_amdgcn_exp2f(__builtin_fmaf(s[knf][qnf][0], sc, -MC));
        float p1 = __builtin_amdgcn_exp2f(__builtin_fmaf(s[knf][qnf][1], sc, -MC));
        float p2 = __builtin_amdgcn_exp2f(__builtin_fmaf(s[knf][qnf][2], sc, -MC));
        float p3 = __builtin_amdgcn_exp2f(__builtin_fmaf(s[knf][qnf][3], sc, -MC));
        unsigned w0 = pk2bf(p0, p1);
        unsigned w1 = pk2bf(p2, p3);
        int gphys = (qnf*4 + knf*2 + (hi>>1)) ^ lo7;
        uint2 wv; wv.x = w0; wv.y = w1;
        *(uint2*)&Pl[lo*64 + gphys*8 + 4*(hi&1)] = wv;
      }
    bf16x8 pa0 = *(const bf16x8*)&Pl[lo*64 + kcof0];
    bf16x8 pa1 = *(const bf16x8*)&Pl[lo*64 + kcof1];
    __builtin_amdgcn_s_setprio(1);
    lac[0] = MFMA16(pa0, ones, lac[0]);
    lac[1] = MFMA16(pa1, ones, lac[1]);
    #pragma unroll
    for (int dhnf=0;dhnf<4;dhnf++){
      bf16x8 vf = *(const bf16x8*)(Vl + (dhnf*16+lo)*64 + vcof);
      o[0][dhnf] = MFMA16(pa0, vf, o[0][dhnf]);
      o[1][dhnf] = MFMA16(pa1, vf, o[1][dhnf]);
    }
    __builtin_amdgcn_s_setprio(0);
    __syncthreads();
    cur ^= 1;
  }
  float* os  = (float*)&Ks[0][0];
  float* lsc = (float*)&Vs[0][0];
  if (wj == 1){
    #pragma unroll
    for (int qnf=0;qnf<2;qnf++){
      #pragma unroll
      for (int dhnf=0;dhnf<4;dhnf++)
        #pragma unroll
        for (int r=0;r<4;r++)
          os[((wi*32 + qnf*16 + 4*hi + r)<<6) + dhnf*16 + lo] = o[qnf][dhnf][r];
      if (lo == 0)
        #pragma unroll
        for (int r=0;r<4;r++)
          lsc[wi*32 + qnf*16 + 4*hi + r] = lac[qnf][r];
    }
  }
  __syncthreads();
  if (wj == 0){
    #pragma unroll
    for (int qnf=0;qnf<2;qnf++)
      #pragma unroll
      for (int r=0;r<4;r++){
        int qloc = wi*32 + qnf*16 + 4*hi + r;
        float lt = lac[qnf][r] + lsc[qloc];
        float rinv = 1.0f / lt;
        #pragma unroll
        for (int dhnf=0;dhnf<4;dhnf++){
          float val = o[qnf][dhnf][r] + os[(qloc<<6) + dhnf*16 + lo];
          O[(size_t)(b*T + qb*64 + qloc)*D + h*64 + dhnf*16 + lo] = f2bf_fast(val * rinv);
        }
      }
  }
}

extern "C" void kernel_launch(void* const* d_in, const int* in_sizes, int n_in,
                              void* d_out, int out_size, void* d_ws, size_t ws_size,
                              hipStream_t stream) {
  const int B=2, T=2048, D=1024;
  const int M = B*T;
  const float* query = (const float*)d_in[0];
  const float* key   = (const float*)d_in[1];
  const float* value = (const float*)d_in[2];
  const float* Wq = (const float*)d_in[3];  const float* bq = (const float*)d_in[4];
  const float* Wk = (const float*)d_in[5];  const float* bk = (const float*)d_in[6];
  const float* Wv = (const float*)d_in[7];  const float* bv = (const float*)d_in[8];
  const float* Wo = (const float*)d_in[9];  const float* bo = (const float*)d_in[10];
  float* out = (float*)d_out;

  char* ws = (char*)d_ws;
  const size_t MB = 1024*1024;
  u16* WqT = (u16*)(ws + 24*MB);
  u16* WkT = (u16*)(ws + 26*MB);
  u16* WvT = (u16*)(ws + 28*MB);
  u16* WoT = (u16*)(ws + 30*MB);
  u16* Qp  = (u16*)(ws + 32*MB);
  u16* Kp  = (u16*)(ws + 40*MB);
  u16* Vp  = (u16*)(ws + 48*MB);
  u16* VTp = (u16*)(ws + 56*MB);
  u16* AO  = (u16*)(ws + 64*MB);

  TwbArgs ta; ta.W[0]=Wq; ta.W[1]=Wk; ta.W[2]=Wv; ta.W[3]=Wo;
  ta.Wt[0]=WqT; ta.Wt[1]=WkT; ta.Wt[2]=WvT; ta.Wt[3]=WoT;
  k_twb4<<<dim3(32,32,4), dim3(32,8), 0, stream>>>(ta);

  GemmArgs3 ga;
  ga.A[0]=query; ga.A[1]=key; ga.A[2]=value;     // fp32 directly; cvt fused
  ga.Bt[0]=WqT; ga.Bt[1]=WkT; ga.Bt[2]=WvT;
  ga.bias[0]=bq; ga.bias[1]=bk; ga.bias[2]=bv;
  ga.C[0]=Qp; ga.C[1]=Kp; ga.C[2]=Vp;
  k_gemm3<<<dim3(32,8,3), 256, 0, stream>>>(ga);

  k_tv<<<dim3(T/32, 2, 32), dim3(32,8), 0, stream>>>(Vp, VTp);
  k_attn<<<dim3(32,32), 256, 0, stream>>>(Qp, Kp, VTp, AO);
  k_gemmO<<<512, 256, 0, stream>>>(AO, WoT, bo, out);
}

// Round 13
// 116.521 us; speedup vs baseline: 1.0597x; 1.0597x over previous
//
#include <hip/hip_runtime.h>

typedef unsigned short u16;
typedef __attribute__((ext_vector_type(4))) float f32x4;
typedef __attribute__((ext_vector_type(8))) short bf16x8;

#define MFMA16(a,b,c) __builtin_amdgcn_mfma_f32_16x16x32_bf16((a),(b),(c),0,0,0)

__device__ inline u16 f2bf(float f){
  union { float f; unsigned u; } v; v.f = f;
  unsigned r = v.u + 0x7FFFu + ((v.u >> 16) & 1u);
  return (u16)(r >> 16);
}
__device__ inline u16 f2bf_fast(float f){
  union { float f; unsigned u; } v; v.f = f;
  return (u16)((v.u + 0x8000u) >> 16);
}
__device__ inline unsigned pk2bf(float x, float y){
  union { float f; unsigned u; } a, b; a.f=x; b.f=y;
  return ((a.u + 0x8000u)>>16) | ((b.u + 0x8000u) & 0xFFFF0000u);
}

typedef const __attribute__((address_space(1))) unsigned int* gas_ptr;
typedef __attribute__((address_space(3))) unsigned int* las_ptr;
__device__ inline void gload_lds16(const u16* g, u16* l){
  __builtin_amdgcn_global_load_lds((gas_ptr)(const void*)g, (las_ptr)(void*)l, 16, 0, 0);
}

// ---------------- fp32 -> bf16 convert, 3 tensors in one launch ----------------
struct CvtArgs { const float* x[3]; u16* y[3]; };
__global__ void k_cvt3(CvtArgs a, int n4){
  const float* x = a.x[blockIdx.y];
  u16* y = a.y[blockIdx.y];
  int i = blockIdx.x*blockDim.x + threadIdx.x;
  if (i < n4){
    float4 v = ((const float4*)x)[i];
    ushort4 o;
    o.x = f2bf(v.x); o.y = f2bf(v.y); o.z = f2bf(v.z); o.w = f2bf(v.w);
    ((ushort4*)y)[i] = o;
  }
}

// ---------------- W (K x N) fp32 -> Wt (N x K) bf16, 4 weights ----------------
struct TwbArgs { const float* W[4]; u16* Wt[4]; };
__global__ void k_twb4(TwbArgs a){
  __shared__ u16 t[32][33];
  const float* W = a.W[blockIdx.z];
  u16* Wt = a.Wt[blockIdx.z];
  int kb = blockIdx.x*32, nb = blockIdx.y*32;
  int tx = threadIdx.x, ty = threadIdx.y;
  #pragma unroll
  for (int i=0;i<32;i+=8)
    t[ty+i][tx] = f2bf(W[(size_t)(kb+ty+i)*1024 + nb+tx]);
  __syncthreads();
  #pragma unroll
  for (int i=0;i<32;i+=8)
    Wt[(size_t)(nb+ty+i)*1024 + kb+tx] = t[tx][ty+i];
}

// ---------------- V (B*T, D) bf16 -> VT (B,H,DH,T) bf16 ----------------
__global__ void k_tv(const u16* __restrict__ V, u16* __restrict__ VT){
  __shared__ u16 t[32][33];
  int tb = blockIdx.x*32;
  int db = blockIdx.y*32;
  int bh = blockIdx.z;
  int b = bh>>4, h = bh&15;
  int tx = threadIdx.x, ty = threadIdx.y;
  #pragma unroll
  for (int i=0;i<32;i+=8)
    t[ty+i][tx] = V[(size_t)(b*2048 + tb+ty+i)*1024 + h*64 + db+tx];
  __syncthreads();
  #pragma unroll
  for (int i=0;i<32;i+=8)
    VT[(size_t)(bh*64 + db+ty+i)*2048 + tb+tx] = t[tx][ty+i];
}

// ---------------- QKV projections: 8-phase 256x256 tile, counted vmcnt ----------------
// 512 threads (8 waves 2Mx4N), BK=64 as 2 K-halves of 32. 4-slot LDS ring per
// tensor [4][256][32] bf16 (128KB). Per K-half: 1 counted vmcnt + 1 raw s_barrier
// (loads stay in flight across barriers - T3/T4), 2 phases of 16 MFMA.
// Swizzle: phys granule = logical ^ ((row>>1)&3) -> conflict-free frag reads.
struct GemmArgs3 { const u16* A[3]; const u16* Bt[3]; const float* bias[3]; u16* C[3]; };

#define STAGE_A(slot, kh) { \
  int c0_ = tid, c1_ = tid + 512; \
  gload_lds16(A + (size_t)(row0 + (c0_>>2))*1024 + (kh)*32 + (((c0_&3) ^ ((c0_>>3)&3))*8), &As[slot][c0_*8]); \
  gload_lds16(A + (size_t)(row0 + (c1_>>2))*1024 + (kh)*32 + (((c1_&3) ^ ((c1_>>3)&3))*8), &As[slot][c1_*8]); }
#define STAGE_B(slot, kh) { \
  int c0_ = tid, c1_ = tid + 512; \
  gload_lds16(Bt + (size_t)(col0 + (c0_>>2))*1024 + (kh)*32 + (((c0_&3) ^ ((c0_>>3)&3))*8), &Bs[slot][c0_*8]); \
  gload_lds16(Bt + (size_t)(col0 + (c1_>>2))*1024 + (kh)*32 + (((c1_&3) ^ ((c1_>>3)&3))*8), &Bs[slot][c1_*8]); }

#define KHALF_BODY(s) { \
  const u16* Al = &As[s][0]; const u16* Bl = &Bs[s][0]; \
  bf16x8 bfr[4], af[4]; \
  _Pragma("unroll") \
  for (int nf=0;nf<4;nf++) \
    bfr[nf] = *(const bf16x8*)(Bl + (wc*64+nf*16+lo)*32 + pg*8); \
  _Pragma("unroll") \
  for (int mf=0;mf<4;mf++) \
    af[mf] = *(const bf16x8*)(Al + (wr*128+mf*16+lo)*32 + pg*8); \
  __builtin_amdgcn_s_setprio(1); \
  _Pragma("unroll") \
  for (int mf=0;mf<4;mf++) \
    _Pragma("unroll") \
    for (int nf=0;nf<4;nf++) \
      acc[mf][nf] = MFMA16(af[mf], bfr[nf], acc[mf][nf]); \
  __builtin_amdgcn_s_setprio(0); \
  STAGE_B_GUARDED \
  _Pragma("unroll") \
  for (int mf=0;mf<4;mf++) \
    af[mf] = *(const bf16x8*)(Al + (wr*128+(mf+4)*16+lo)*32 + pg*8); \
  __builtin_amdgcn_s_setprio(1); \
  _Pragma("unroll") \
  for (int mf=0;mf<4;mf++) \
    _Pragma("unroll") \
    for (int nf=0;nf<4;nf++) \
      acc[mf+4][nf] = MFMA16(af[mf], bfr[nf], acc[mf+4][nf]); \
  __builtin_amdgcn_s_setprio(0); }

__global__ __launch_bounds__(512) void k_gemm3(GemmArgs3 g){
  const int N=1024;
  __shared__ __attribute__((aligned(16))) u16 As[4][256*32];
  __shared__ __attribute__((aligned(16))) u16 Bs[4][256*32];
  int flat = blockIdx.x;                 // 192 blocks = 8 XCD x 24
  int swz = (flat&7)*24 + (flat>>3);
  int bz = swz>>6, rem = swz&63;
  int bx = rem>>2, by = rem&3;
  const u16* A = g.A[bz]; const u16* Bt = g.Bt[bz];
  const float* bias = g.bias[bz]; u16* C = g.C[bz];
  const int tid = threadIdx.x;
  const int wave = tid>>6, lane = tid&63;
  const int lo = lane&15, hi = lane>>4;
  const int wr = wave>>2, wc = wave&3;
  const int row0 = bx*256, col0 = by*256;
  const int pg = hi ^ ((lo>>1)&3);       // physical granule for frag reads

  f32x4 acc[8][4];
  #pragma unroll
  for (int i=0;i<8;i++)
    #pragma unroll
    for (int j=0;j<4;j++) acc[i][j] = (f32x4){0.f,0.f,0.f,0.f};

  // prologue: stage K-halves 0,1,2 (A+B each) -> 12 loads
  STAGE_A(0,0); STAGE_B(0,0);
  STAGE_A(1,1); STAGE_B(1,1);
  STAGE_A(2,2); STAGE_B(2,2);

  // main: K-halves 0..28 (stages on, vmcnt(10) = 2.5 K-halves in flight)
  for (int h = 0; h < 29; ++h){
    const int s = h & 3;
    STAGE_A((h+3)&3, h+3);
    asm volatile("s_waitcnt vmcnt(10)" ::: "memory");
    __builtin_amdgcn_s_barrier();
    #define STAGE_B_GUARDED STAGE_B((h+3)&3, h+3);
    KHALF_BODY(s)
    #undef STAGE_B_GUARDED
  }
  // tail: K-halves 29,30,31 (no stages; tightening vmcnt)
  {
    asm volatile("s_waitcnt vmcnt(8)" ::: "memory");
    __builtin_amdgcn_s_barrier();
    #define STAGE_B_GUARDED
    KHALF_BODY(29&3)
    #undef STAGE_B_GUARDED
  }
  {
    asm volatile("s_waitcnt vmcnt(4)" ::: "memory");
    __builtin_amdgcn_s_barrier();
    #define STAGE_B_GUARDED
    KHALF_BODY(30&3)
    #undef STAGE_B_GUARDED
  }
  {
    asm volatile("s_waitcnt vmcnt(0)" ::: "memory");
    __builtin_amdgcn_s_barrier();
    #define STAGE_B_GUARDED
    KHALF_BODY(31&3)
    #undef STAGE_B_GUARDED
  }

  #pragma unroll
  for (int mf=0;mf<8;mf++){
    #pragma unroll
    for (int nf=0;nf<4;nf++){
      int r0 = row0 + wr*128 + mf*16 + hi*4;
      int c0 = col0 + wc*64 + nf*16 + lo;
      float bv = bias[c0];
      #pragma unroll
      for (int r=0;r<4;r++)
        C[(size_t)(r0+r)*N + c0] = f2bf(acc[mf][nf][r] + bv);
    }
  }
}

// ---------------- O projection: 64x128 tiles, 512 blocks (2/CU) ----------------
__global__ __launch_bounds__(256) void k_gemmO(const u16* __restrict__ A, const u16* __restrict__ Bt,
                                               const float* __restrict__ bias, float* __restrict__ C){
  const int N=1024, K=1024;
  int f = blockIdx.x;
  int xcd = f & 7, idx = f >> 3;
  int bx = xcd*8 + (idx>>3), by = idx & 7;   // row-stripe per XCD
  __shared__ __attribute__((aligned(16))) u16 As[64*64];
  __shared__ __attribute__((aligned(16))) u16 Bs[128*64];
  const int tid  = threadIdx.x;
  const int wave = tid>>6, lane = tid&63;
  const int lo = lane&15, hi = lane>>4;
  const int row0 = bx*64, col0 = by*128;
  const int wm = (wave>>1)*32, wn = (wave&1)*64;
  f32x4 acc[2][4];
  #pragma unroll
  for (int i=0;i<2;i++)
    #pragma unroll
    for (int j=0;j<4;j++) acc[i][j] = (f32x4){0.f,0.f,0.f,0.f};

  for (int k0=0; k0<K; k0+=64){
    #pragma unroll
    for (int r=0;r<2;r++){
      int c = r*256 + tid;
      gload_lds16(A + (size_t)(row0 + (c>>3))*K + k0 + (c&7)*8, As + c*8);
    }
    #pragma unroll
    for (int r=0;r<4;r++){
      int c = r*256 + tid;
      gload_lds16(Bt + (size_t)(col0 + (c>>3))*K + k0 + (c&7)*8, Bs + c*8);
    }
    __syncthreads();
    __builtin_amdgcn_s_setprio(1);
    #pragma unroll
    for (int ks=0;ks<2;ks++){
      bf16x8 af[2], bfr[4];
      #pragma unroll
      for (int mf=0;mf<2;mf++)
        af[mf] = *(const bf16x8*)(As + (wm+mf*16+lo)*64 + ks*32 + hi*8);
      #pragma unroll
      for (int nf=0;nf<4;nf++)
        bfr[nf] = *(const bf16x8*)(Bs + (wn+nf*16+lo)*64 + ks*32 + hi*8);
      #pragma unroll
      for (int mf=0;mf<2;mf++)
        #pragma unroll
        for (int nf=0;nf<4;nf++)
          acc[mf][nf] = MFMA16(af[mf], bfr[nf], acc[mf][nf]);
    }
    __builtin_amdgcn_s_setprio(0);
    __syncthreads();
  }
  #pragma unroll
  for (int mf=0;mf<2;mf++){
    #pragma unroll
    for (int nf=0;nf<4;nf++){
      int r0 = row0 + wm + mf*16 + hi*4;
      int c0 = col0 + wn + nf*16 + lo;
      float bv = bias[c0];
      #pragma unroll
      for (int r=0;r<4;r++)
        C[(size_t)(r0+r)*N + c0] = acc[mf][nf][r] + bv;
    }
  }
}

// ---------------- flash attention (causal), v10 (proven): 2x2 wave split ----------------
__global__ __launch_bounds__(256) void k_attn(
    const u16* __restrict__ Q, const u16* __restrict__ Kp,
    const u16* __restrict__ VT, u16* __restrict__ O)
{
  const int T=2048, D=1024;
  __shared__ __attribute__((aligned(16))) u16 Ks[2][64*64];
  __shared__ __attribute__((aligned(16))) u16 Vs[2][64*64];
  __shared__ __attribute__((aligned(16))) u16 Plds[4][16*64];
  int f = blockIdx.x + (blockIdx.y<<5);
  int xcd = f & 7, idx = f >> 3;
  const int bh = (xcd<<2) | (idx&3);
  const int qb = 31 - (idx>>2);
  const int b = bh>>4, h = bh&15;
  const int tid = threadIdx.x;
  const int wave = tid>>6, lane = tid&63;
  const int lo = lane&15, hi = lane>>4;
  const int wi = wave>>1, wj = wave&1;
  const int lo7 = lo&7;
  const float NEG = -1e30f;
  const float sc = 0.125f * 1.44269504f;
  const float MC = 64.0f * sc;
  const bf16x8 ones = {0x3F80,0x3F80,0x3F80,0x3F80,0x3F80,0x3F80,0x3F80,0x3F80};

  const int c0 = tid, c1 = 256 + tid;
  const int sr0 = c0>>3, sj0 = (c0&7)^(sr0&7);
  const int sr1 = c1>>3, sj1 = (c1&7)^(sr1&7);
  const u16* Kbase = Kp + (size_t)(b*T)*D + h*64;
  const u16* Vbase = VT + (size_t)(bh*64)*T;
  const size_t kOff0 = (size_t)sr0*D + sj0*8, kOff1 = (size_t)sr1*D + sj1*8;
  const size_t vOff0 = (size_t)sr0*T + sj0*8, vOff1 = (size_t)sr1*T + sj1*8;

  const int qrow0 = qb*64 + wi*32;
  bf16x8 qf[2][2];
  #pragma unroll
  for (int qnf=0;qnf<2;qnf++){
    const u16* Qr = Q + (size_t)(b*T + qrow0 + qnf*16 + lo)*D + h*64;
    qf[qnf][0] = *(const bf16x8*)(Qr + hi*8);
    qf[qnf][1] = *(const bf16x8*)(Qr + 32 + hi*8);
  }

  f32x4 o[2][4];
  #pragma unroll
  for (int i=0;i<2;i++)
    #pragma unroll
    for (int j=0;j<4;j++) o[i][j] = (f32x4){0.f,0.f,0.f,0.f};
  f32x4 lac[2];
  lac[0] = (f32x4){0.f,0.f,0.f,0.f};
  lac[1] = (f32x4){0.f,0.f,0.f,0.f};

  gload_lds16(Kbase + kOff0, &Ks[0][c0*8]);
  gload_lds16(Kbase + kOff1, &Ks[0][c1*8]);
  gload_lds16(Vbase + vOff0, &Vs[0][c0*8]);
  gload_lds16(Vbase + vOff1, &Vs[0][c1*8]);
  __syncthreads();

  u16* Pl = &Plds[wave][0];
  const int kcof0 = ((     hi) ^ lo7)*8;
  const int kcof1 = (( 4 + hi) ^ lo7)*8;
  const int vcof  = ((wj*4+hi) ^ lo7)*8;

  int cur = 0;
  for (int kb=0; kb<=qb; kb++){
    if (kb < qb){
      const u16* Kt = Kbase + (size_t)(kb+1)*64*D;
      const u16* Vt = Vbase + (kb+1)*64;
      gload_lds16(Kt + kOff0, &Ks[cur^1][c0*8]);
      gload_lds16(Kt + kOff1, &Ks[cur^1][c1*8]);
      gload_lds16(Vt + vOff0, &Vs[cur^1][c0*8]);
      gload_lds16(Vt + vOff1, &Vs[cur^1][c1*8]);
    }
    const u16* Kl = Ks[cur];
    const u16* Vl = Vs[cur];
    f32x4 s[2][2];
    __builtin_amdgcn_s_setprio(1);
    #pragma unroll
    for (int knf=0;knf<2;knf++){
      int krow = wj*32 + knf*16 + lo;
      bf16x8 kf0 = *(const bf16x8*)(Kl + krow*64 + kcof0);
      bf16x8 kf1 = *(const bf16x8*)(Kl + krow*64 + kcof1);
      #pragma unroll
      for (int qnf=0;qnf<2;qnf++){
        f32x4 z = (f32x4){0.f,0.f,0.f,0.f};
        z = MFMA16(kf0, qf[qnf][0], z);
        s[knf][qnf] = MFMA16(kf1, qf[qnf][1], z);
      }
    }
    __builtin_amdgcn_s_setprio(0);
    if (kb == qb){
      int ql = wi*32 + lo;
      #pragma unroll
      for (int knf=0;knf<2;knf++){
        int kl0 = wj*32 + knf*16 + 4*hi;
        #pragma unroll
        for (int qnf=0;qnf<2;qnf++){
          int qv = ql + qnf*16;
          #pragma unroll
          for (int r=0;r<4;r++)
            if (kl0 + r > qv) s[knf][qnf][r] = NEG;
        }
      }
    }
    #pragma unroll
    for (int knf=0;knf<2;knf++)
      #pragma unroll
      for (int qnf=0;qnf<2;qnf++){
        float p0 = __builtin_amdgcn_exp2f(__builtin_fmaf(s[knf][qnf][0], sc, -MC));
        float p1 = __builtin_amdgcn_exp2f(__builtin_fmaf(s[knf][qnf][1], sc, -MC));
        float p2 = __builtin_amdgcn_exp2f(__builtin_fmaf(s[knf][qnf][2], sc, -MC));
        float p3 = __builtin_amdgcn_exp2f(__builtin_fmaf(s[knf][qnf][3], sc, -MC));
        unsigned w0 = pk2bf(p0, p1);
        unsigned w1 = pk2bf(p2, p3);
        int gphys = (qnf*4 + knf*2 + (hi>>1)) ^ lo7;
        uint2 wv; wv.x = w0; wv.y = w1;
        *(uint2*)&Pl[lo*64 + gphys*8 + 4*(hi&1)] = wv;
      }
    bf16x8 pa0 = *(const bf16x8*)&Pl[lo*64 + kcof0];
    bf16x8 pa1 = *(const bf16x8*)&Pl[lo*64 + kcof1];
    __builtin_amdgcn_s_setprio(1);
    lac[0] = MFMA16(pa0, ones, lac[0]);
    lac[1] = MFMA16(pa1, ones, lac[1]);
    #pragma unroll
    for (int dhnf=0;dhnf<4;dhnf++){
      bf16x8 vf = *(const bf16x8*)(Vl + (dhnf*16+lo)*64 + vcof);
      o[0][dhnf] = MFMA16(pa0, vf, o[0][dhnf]);
      o[1][dhnf] = MFMA16(pa1, vf, o[1][dhnf]);
    }
    __builtin_amdgcn_s_setprio(0);
    __syncthreads();
    cur ^= 1;
  }
  float* os  = (float*)&Ks[0][0];
  float* lsc = (float*)&Vs[0][0];
  if (wj == 1){
    #pragma unroll
    for (int qnf=0;qnf<2;qnf++){
      #pragma unroll
      for (int dhnf=0;dhnf<4;dhnf++)
        #pragma unroll
        for (int r=0;r<4;r++)
          os[((wi*32 + qnf*16 + 4*hi + r)<<6) + dhnf*16 + lo] = o[qnf][dhnf][r];
      if (lo == 0)
        #pragma unroll
        for (int r=0;r<4;r++)
          lsc[wi*32 + qnf*16 + 4*hi + r] = lac[qnf][r];
    }
  }
  __syncthreads();
  if (wj == 0){
    #pragma unroll
    for (int qnf=0;qnf<2;qnf++)
      #pragma unroll
      for (int r=0;r<4;r++){
        int qloc = wi*32 + qnf*16 + 4*hi + r;
        float lt = lac[qnf][r] + lsc[qloc];
        float rinv = 1.0f / lt;
        #pragma unroll
        for (int dhnf=0;dhnf<4;dhnf++){
          float val = o[qnf][dhnf][r] + os[(qloc<<6) + dhnf*16 + lo];
          O[(size_t)(b*T + qb*64 + qloc)*D + h*64 + dhnf*16 + lo] = f2bf_fast(val * rinv);
        }
      }
  }
}

extern "C" void kernel_launch(void* const* d_in, const int* in_sizes, int n_in,
                              void* d_out, int out_size, void* d_ws, size_t ws_size,
                              hipStream_t stream) {
  const int B=2, T=2048, D=1024;
  const int M = B*T;
  const float* query = (const float*)d_in[0];
  const float* key   = (const float*)d_in[1];
  const float* value = (const float*)d_in[2];
  const float* Wq = (const float*)d_in[3];  const float* bq = (const float*)d_in[4];
  const float* Wk = (const float*)d_in[5];  const float* bk = (const float*)d_in[6];
  const float* Wv = (const float*)d_in[7];  const float* bv = (const float*)d_in[8];
  const float* Wo = (const float*)d_in[9];  const float* bo = (const float*)d_in[10];
  float* out = (float*)d_out;

  char* ws = (char*)d_ws;
  const size_t MB = 1024*1024;
  u16* xq  = (u16*)(ws + 0*MB);
  u16* xk  = (u16*)(ws + 8*MB);
  u16* xv  = (u16*)(ws + 16*MB);
  u16* WqT = (u16*)(ws + 24*MB);
  u16* WkT = (u16*)(ws + 26*MB);
  u16* WvT = (u16*)(ws + 28*MB);
  u16* WoT = (u16*)(ws + 30*MB);
  u16* Qp  = (u16*)(ws + 32*MB);
  u16* Kp  = (u16*)(ws + 40*MB);
  u16* Vp  = (u16*)(ws + 48*MB);
  u16* VTp = (u16*)(ws + 56*MB);
  u16* AO  = (u16*)(ws + 64*MB);

  int n4 = M*D/4;
  CvtArgs ca; ca.x[0]=query; ca.x[1]=key; ca.x[2]=value; ca.y[0]=xq; ca.y[1]=xk; ca.y[2]=xv;
  k_cvt3<<<dim3(n4/256, 3), 256, 0, stream>>>(ca, n4);

  TwbArgs ta; ta.W[0]=Wq; ta.W[1]=Wk; ta.W[2]=Wv; ta.W[3]=Wo;
  ta.Wt[0]=WqT; ta.Wt[1]=WkT; ta.Wt[2]=WvT; ta.Wt[3]=WoT;
  k_twb4<<<dim3(32,32,4), dim3(32,8), 0, stream>>>(ta);

  GemmArgs3 ga;
  ga.A[0]=xq; ga.A[1]=xk; ga.A[2]=xv;
  ga.Bt[0]=WqT; ga.Bt[1]=WkT; ga.Bt[2]=WvT;
  ga.bias[0]=bq; ga.bias[1]=bk; ga.bias[2]=bv;
  ga.C[0]=Qp; ga.C[1]=Kp; ga.C[2]=Vp;
  k_gemm3<<<192, 512, 0, stream>>>(ga);

  k_tv<<<dim3(T/32, 2, 32), dim3(32,8), 0, stream>>>(Vp, VTp);
  k_attn<<<dim3(32,32), 256, 0, stream>>>(Qp, Kp, VTp, AO);
  k_gemmO<<<512, 256, 0, stream>>>(AO, WoT, bo, out);
}

// Round 14
// 113.260 us; speedup vs baseline: 1.0902x; 1.0288x over previous
//
#include <hip/hip_runtime.h>

typedef unsigned short u16;
typedef __attribute__((ext_vector_type(4))) float f32x4;
typedef __attribute__((ext_vector_type(8))) short bf16x8;

#define MFMA16(a,b,c) __builtin_amdgcn_mfma_f32_16x16x32_bf16((a),(b),(c),0,0,0)

__device__ inline u16 f2bf(float f){
  union { float f; unsigned u; } v; v.f = f;
  unsigned r = v.u + 0x7FFFu + ((v.u >> 16) & 1u);
  return (u16)(r >> 16);
}
__device__ inline u16 f2bf_fast(float f){
  union { float f; unsigned u; } v; v.f = f;
  return (u16)((v.u + 0x8000u) >> 16);
}
__device__ inline unsigned pk2bf(float x, float y){
  union { float f; unsigned u; } a, b; a.f=x; b.f=y;
  return ((a.u + 0x8000u)>>16) | ((b.u + 0x8000u) & 0xFFFF0000u);
}

typedef const __attribute__((address_space(1))) unsigned int* gas_ptr;
typedef __attribute__((address_space(3))) unsigned int* las_ptr;
__device__ inline void gload_lds16(const u16* g, u16* l){
  __builtin_amdgcn_global_load_lds((gas_ptr)(const void*)g, (las_ptr)(void*)l, 16, 0, 0);
}

// ---------------- prep: fp32->bf16 cvt (3 tensors) + weight transpose (4), one launch ----------------
struct PrepArgs { const float* x[3]; u16* y[3]; const float* W[4]; u16* Wt[4]; };
__global__ void k_prep(PrepArgs a){
  __shared__ u16 t[32][33];
  int blk = blockIdx.x;
  int tid = threadIdx.x;
  if (blk < 12288){
    int tn = blk >> 12;                  // 4096 blocks per tensor (n4 = 1048576)
    int i  = (blk & 4095)*256 + tid;
    float4 v = ((const float4*)a.x[tn])[i];
    ushort4 o;
    o.x = f2bf(v.x); o.y = f2bf(v.y); o.z = f2bf(v.z); o.w = f2bf(v.w);
    ((ushort4*)a.y[tn])[i] = o;
  } else {
    int w = blk - 12288;                 // 0..4095
    int z = w >> 10;
    int xy = w & 1023;
    int kb = (xy & 31)*32, nb = (xy >> 5)*32;
    const float* W = a.W[z];
    u16* Wt = a.Wt[z];
    int tx = tid & 31, ty = tid >> 5;    // 32 x 8
    #pragma unroll
    for (int i=0;i<32;i+=8)
      t[ty+i][tx] = f2bf(W[(size_t)(kb+ty+i)*1024 + nb+tx]);
    __syncthreads();
    #pragma unroll
    for (int i=0;i<32;i+=8)
      Wt[(size_t)(nb+ty+i)*1024 + kb+tx] = t[tx][ty+i];
  }
}

// ---------------- V (B*T, D) bf16 -> VT (B,H,DH,T) bf16 ----------------
__global__ void k_tv(const u16* __restrict__ V, u16* __restrict__ VT){
  __shared__ u16 t[32][33];
  int tb = blockIdx.x*32;
  int db = blockIdx.y*32;
  int bh = blockIdx.z;
  int b = bh>>4, h = bh&15;
  int tx = threadIdx.x, ty = threadIdx.y;
  #pragma unroll
  for (int i=0;i<32;i+=8)
    t[ty+i][tx] = V[(size_t)(b*2048 + tb+ty+i)*1024 + h*64 + db+tx];
  __syncthreads();
  #pragma unroll
  for (int i=0;i<32;i+=8)
    VT[(size_t)(bh*64 + db+ty+i)*2048 + tb+tx] = t[tx][ty+i];
}

// ---------------- QKV projections: 256x256, 4-slot ring, m201 per-phase interleave ----------------
// 512 threads (8 waves 2Mx4N), K-halves of 32. Per K-half: 2 phases, each
// {ds_reads + stage-issue -> s_barrier -> lgkmcnt(0) -> 16 MFMA -> s_barrier}.
// Counted vmcnt(8) once per K-half (2 slots stay in flight across barriers).
struct GemmArgs3 { const u16* A[3]; const u16* Bt[3]; const float* bias[3]; u16* C[3]; };

#define STAGE_A(slot, kh) { \
  int c0_ = tid, c1_ = tid + 512; \
  gload_lds16(A + (size_t)(row0 + (c0_>>2))*1024 + (kh)*32 + (((c0_&3) ^ ((c0_>>3)&3))*8), &As[slot][c0_*8]); \
  gload_lds16(A + (size_t)(row0 + (c1_>>2))*1024 + (kh)*32 + (((c1_&3) ^ ((c1_>>3)&3))*8), &As[slot][c1_*8]); }
#define STAGE_B(slot, kh) { \
  int c0_ = tid, c1_ = tid + 512; \
  gload_lds16(Bt + (size_t)(col0 + (c0_>>2))*1024 + (kh)*32 + (((c0_&3) ^ ((c0_>>3)&3))*8), &Bs[slot][c0_*8]); \
  gload_lds16(Bt + (size_t)(col0 + (c1_>>2))*1024 + (kh)*32 + (((c1_&3) ^ ((c1_>>3)&3))*8), &Bs[slot][c1_*8]); }

#define PHASE1(s, STAGE_STMT) { \
  const u16* Al = &As[s][0]; const u16* Bl = &Bs[s][0]; \
  _Pragma("unroll") \
  for (int nf=0;nf<4;nf++) \
    bfr[nf] = *(const bf16x8*)(Bl + (wc*64+nf*16+lo)*32 + pg*8); \
  _Pragma("unroll") \
  for (int mf=0;mf<4;mf++) \
    af[mf] = *(const bf16x8*)(Al + (wr*128+mf*16+lo)*32 + pg*8); \
  STAGE_STMT \
  __builtin_amdgcn_s_barrier(); \
  asm volatile("s_waitcnt lgkmcnt(0)" ::: "memory"); \
  __builtin_amdgcn_s_setprio(1); \
  _Pragma("unroll") \
  for (int mf=0;mf<4;mf++) \
    _Pragma("unroll") \
    for (int nf=0;nf<4;nf++) \
      acc[mf][nf] = MFMA16(af[mf], bfr[nf], acc[mf][nf]); \
  __builtin_amdgcn_s_setprio(0); \
  __builtin_amdgcn_s_barrier(); }

#define PHASE2(s, STAGE_STMT, VM_STMT) { \
  const u16* Al = &As[s][0]; \
  _Pragma("unroll") \
  for (int mf=0;mf<4;mf++) \
    af[mf] = *(const bf16x8*)(Al + (wr*128+(mf+4)*16+lo)*32 + pg*8); \
  STAGE_STMT \
  VM_STMT \
  __builtin_amdgcn_s_barrier(); \
  asm volatile("s_waitcnt lgkmcnt(0)" ::: "memory"); \
  __builtin_amdgcn_s_setprio(1); \
  _Pragma("unroll") \
  for (int mf=0;mf<4;mf++) \
    _Pragma("unroll") \
    for (int nf=0;nf<4;nf++) \
      acc[mf+4][nf] = MFMA16(af[mf], bfr[nf], acc[mf+4][nf]); \
  __builtin_amdgcn_s_setprio(0); \
  __builtin_amdgcn_s_barrier(); }

__global__ __launch_bounds__(512) void k_gemm3(GemmArgs3 g){
  const int N=1024;
  __shared__ __attribute__((aligned(16))) u16 As[4][256*32];
  __shared__ __attribute__((aligned(16))) u16 Bs[4][256*32];
  int flat = blockIdx.x;                 // 192 blocks = 8 XCD x 24
  int swz = (flat&7)*24 + (flat>>3);
  int bz = swz>>6, rem = swz&63;
  int bx = rem>>2, by = rem&3;
  const u16* A = g.A[bz]; const u16* Bt = g.Bt[bz];
  const float* bias = g.bias[bz]; u16* C = g.C[bz];
  const int tid = threadIdx.x;
  const int wave = tid>>6, lane = tid&63;
  const int lo = lane&15, hi = lane>>4;
  const int wr = wave>>2, wc = wave&3;
  const int row0 = bx*256, col0 = by*256;
  const int pg = hi ^ ((lo>>1)&3);

  f32x4 acc[8][4];
  #pragma unroll
  for (int i=0;i<8;i++)
    #pragma unroll
    for (int j=0;j<4;j++) acc[i][j] = (f32x4){0.f,0.f,0.f,0.f};

  // prologue: stage slots 0,1,2 (A+B interleaved, 12 loads), retire slot 0
  STAGE_A(0,0); STAGE_B(0,0);
  STAGE_A(1,1); STAGE_B(1,1);
  STAGE_A(2,2); STAGE_B(2,2);
  asm volatile("s_waitcnt vmcnt(8)" ::: "memory");   // slot 0 landed
  __builtin_amdgcn_s_barrier();

  bf16x8 bfr[4], af[4];
  // main: h = 0..28 (stages for h+3; vmcnt(8) retires slot h+1)
  for (int h = 0; h < 29; ++h){
    const int s = h & 3;
    const int s3 = (h+3) & 3;
    PHASE1(s, STAGE_A(s3, h+3);)
    PHASE2(s, STAGE_B(s3, h+3);, asm volatile("s_waitcnt vmcnt(8)" ::: "memory");)
  }
  // tail: h = 29,30,31 (no stages; tightening vmcnt)
  PHASE1(1, )
  PHASE2(1, , asm volatile("s_waitcnt vmcnt(4)" ::: "memory");)
  PHASE1(2, )
  PHASE2(2, , asm volatile("s_waitcnt vmcnt(0)" ::: "memory");)
  PHASE1(3, )
  PHASE2(3, , )

  #pragma unroll
  for (int mf=0;mf<8;mf++){
    #pragma unroll
    for (int nf=0;nf<4;nf++){
      int r0 = row0 + wr*128 + mf*16 + hi*4;
      int c0 = col0 + wc*64 + nf*16 + lo;
      float bv = bias[c0];
      #pragma unroll
      for (int r=0;r<4;r++)
        C[(size_t)(r0+r)*N + c0] = f2bf(acc[mf][nf][r] + bv);
    }
  }
}

// ---------------- O projection: 64x128 tiles, 512 blocks (2/CU) ----------------
__global__ __launch_bounds__(256) void k_gemmO(const u16* __restrict__ A, const u16* __restrict__ Bt,
                                               const float* __restrict__ bias, float* __restrict__ C){
  const int N=1024, K=1024;
  int f = blockIdx.x;
  int xcd = f & 7, idx = f >> 3;
  int bx = xcd*8 + (idx>>3), by = idx & 7;   // row-stripe per XCD
  __shared__ __attribute__((aligned(16))) u16 As[64*64];
  __shared__ __attribute__((aligned(16))) u16 Bs[128*64];
  const int tid  = threadIdx.x;
  const int wave = tid>>6, lane = tid&63;
  const int lo = lane&15, hi = lane>>4;
  const int row0 = bx*64, col0 = by*128;
  const int wm = (wave>>1)*32, wn = (wave&1)*64;
  f32x4 acc[2][4];
  #pragma unroll
  for (int i=0;i<2;i++)
    #pragma unroll
    for (int j=0;j<4;j++) acc[i][j] = (f32x4){0.f,0.f,0.f,0.f};

  for (int k0=0; k0<K; k0+=64){
    #pragma unroll
    for (int r=0;r<2;r++){
      int c = r*256 + tid;
      gload_lds16(A + (size_t)(row0 + (c>>3))*K + k0 + (c&7)*8, As + c*8);
    }
    #pragma unroll
    for (int r=0;r<4;r++){
      int c = r*256 + tid;
      gload_lds16(Bt + (size_t)(col0 + (c>>3))*K + k0 + (c&7)*8, Bs + c*8);
    }
    __syncthreads();
    __builtin_amdgcn_s_setprio(1);
    #pragma unroll
    for (int ks=0;ks<2;ks++){
      bf16x8 af[2], bfr[4];
      #pragma unroll
      for (int mf=0;mf<2;mf++)
        af[mf] = *(const bf16x8*)(As + (wm+mf*16+lo)*64 + ks*32 + hi*8);
      #pragma unroll
      for (int nf=0;nf<4;nf++)
        bfr[nf] = *(const bf16x8*)(Bs + (wn+nf*16+lo)*64 + ks*32 + hi*8);
      #pragma unroll
      for (int mf=0;mf<2;mf++)
        #pragma unroll
        for (int nf=0;nf<4;nf++)
          acc[mf][nf] = MFMA16(af[mf], bfr[nf], acc[mf][nf]);
    }
    __builtin_amdgcn_s_setprio(0);
    __syncthreads();
  }
  #pragma unroll
  for (int mf=0;mf<2;mf++){
    #pragma unroll
    for (int nf=0;nf<4;nf++){
      int r0 = row0 + wm + mf*16 + hi*4;
      int c0 = col0 + wn + nf*16 + lo;
      float bv = bias[c0];
      #pragma unroll
      for (int r=0;r<4;r++)
        C[(size_t)(r0+r)*N + c0] = acc[mf][nf][r] + bv;
    }
  }
}

// ---------------- flash attention (causal), v10 (proven): 2x2 wave split ----------------
__global__ __launch_bounds__(256) void k_attn(
    const u16* __restrict__ Q, const u16* __restrict__ Kp,
    const u16* __restrict__ VT, u16* __restrict__ O)
{
  const int T=2048, D=1024;
  __shared__ __attribute__((aligned(16))) u16 Ks[2][64*64];
  __shared__ __attribute__((aligned(16))) u16 Vs[2][64*64];
  __shared__ __attribute__((aligned(16))) u16 Plds[4][16*64];
  int f = blockIdx.x + (blockIdx.y<<5);
  int xcd = f & 7, idx = f >> 3;
  const int bh = (xcd<<2) | (idx&3);
  const int qb = 31 - (idx>>2);
  const int b = bh>>4, h = bh&15;
  const int tid = threadIdx.x;
  const int wave = tid>>6, lane = tid&63;
  const int lo = lane&15, hi = lane>>4;
  const int wi = wave>>1, wj = wave&1;
  const int lo7 = lo&7;
  const float NEG = -1e30f;
  const float sc = 0.125f * 1.44269504f;
  const float MC = 64.0f * sc;
  const bf16x8 ones = {0x3F80,0x3F80,0x3F80,0x3F80,0x3F80,0x3F80,0x3F80,0x3F80};

  const int c0 = tid, c1 = 256 + tid;
  const int sr0 = c0>>3, sj0 = (c0&7)^(sr0&7);
  const int sr1 = c1>>3, sj1 = (c1&7)^(sr1&7);
  const u16* Kbase = Kp + (size_t)(b*T)*D + h*64;
  const u16* Vbase = VT + (size_t)(bh*64)*T;
  const size_t kOff0 = (size_t)sr0*D + sj0*8, kOff1 = (size_t)sr1*D + sj1*8;
  const size_t vOff0 = (size_t)sr0*T + sj0*8, vOff1 = (size_t)sr1*T + sj1*8;

  const int qrow0 = qb*64 + wi*32;
  bf16x8 qf[2][2];
  #pragma unroll
  for (int qnf=0;qnf<2;qnf++){
    const u16* Qr = Q + (size_t)(b*T + qrow0 + qnf*16 + lo)*D + h*64;
    qf[qnf][0] = *(const bf16x8*)(Qr + hi*8);
    qf[qnf][1] = *(const bf16x8*)(Qr + 32 + hi*8);
  }

  f32x4 o[2][4];
  #pragma unroll
  for (int i=0;i<2;i++)
    #pragma unroll
    for (int j=0;j<4;j++) o[i][j] = (f32x4){0.f,0.f,0.f,0.f};
  f32x4 lac[2];
  lac[0] = (f32x4){0.f,0.f,0.f,0.f};
  lac[1] = (f32x4){0.f,0.f,0.f,0.f};

  gload_lds16(Kbase + kOff0, &Ks[0][c0*8]);
  gload_lds16(Kbase + kOff1, &Ks[0][c1*8]);
  gload_lds16(Vbase + vOff0, &Vs[0][c0*8]);
  gload_lds16(Vbase + vOff1, &Vs[0][c1*8]);
  __syncthreads();

  u16* Pl = &Plds[wave][0];
  const int kcof0 = ((     hi) ^ lo7)*8;
  const int kcof1 = (( 4 + hi) ^ lo7)*8;
  const int vcof  = ((wj*4+hi) ^ lo7)*8;

  int cur = 0;
  for (int kb=0; kb<=qb; kb++){
    if (kb < qb){
      const u16* Kt = Kbase + (size_t)(kb+1)*64*D;
      const u16* Vt = Vbase + (kb+1)*64;
      gload_lds16(Kt + kOff0, &Ks[cur^1][c0*8]);
      gload_lds16(Kt + kOff1, &Ks[cur^1][c1*8]);
      gload_lds16(Vt + vOff0, &Vs[cur^1][c0*8]);
      gload_lds16(Vt + vOff1, &Vs[cur^1][c1*8]);
    }
    const u16* Kl = Ks[cur];
    const u16* Vl = Vs[cur];
    f32x4 s[2][2];
    __builtin_amdgcn_s_setprio(1);
    #pragma unroll
    for (int knf=0;knf<2;knf++){
      int krow = wj*32 + knf*16 + lo;
      bf16x8 kf0 = *(const bf16x8*)(Kl + krow*64 + kcof0);
      bf16x8 kf1 = *(const bf16x8*)(Kl + krow*64 + kcof1);
      #pragma unroll
      for (int qnf=0;qnf<2;qnf++){
        f32x4 z = (f32x4){0.f,0.f,0.f,0.f};
        z = MFMA16(kf0, qf[qnf][0], z);
        s[knf][qnf] = MFMA16(kf1, qf[qnf][1], z);
      }
    }
    __builtin_amdgcn_s_setprio(0);
    if (kb == qb){
      int ql = wi*32 + lo;
      #pragma unroll
      for (int knf=0;knf<2;knf++){
        int kl0 = wj*32 + knf*16 + 4*hi;
        #pragma unroll
        for (int qnf=0;qnf<2;qnf++){
          int qv = ql + qnf*16;
          #pragma unroll
          for (int r=0;r<4;r++)
            if (kl0 + r > qv) s[knf][qnf][r] = NEG;
        }
      }
    }
    #pragma unroll
    for (int knf=0;knf<2;knf++)
      #pragma unroll
      for (int qnf=0;qnf<2;qnf++){
        float p0 = __builtin_amdgcn_exp2f(__builtin_fmaf(s[knf][qnf][0], sc, -MC));
        float p1 = __builtin_amdgcn_exp2f(__builtin_fmaf(s[knf][qnf][1], sc, -MC));
        float p2 = __builtin_amdgcn_exp2f(__builtin_fmaf(s[knf][qnf][2], sc, -MC));
        float p3 = __builtin_amdgcn_exp2f(__builtin_fmaf(s[knf][qnf][3], sc, -MC));
        unsigned w0 = pk2bf(p0, p1);
        unsigned w1 = pk2bf(p2, p3);
        int gphys = (qnf*4 + knf*2 + (hi>>1)) ^ lo7;
        uint2 wv; wv.x = w0; wv.y = w1;
        *(uint2*)&Pl[lo*64 + gphys*8 + 4*(hi&1)] = wv;
      }
    bf16x8 pa0 = *(const bf16x8*)&Pl[lo*64 + kcof0];
    bf16x8 pa1 = *(const bf16x8*)&Pl[lo*64 + kcof1];
    __builtin_amdgcn_s_setprio(1);
    lac[0] = MFMA16(pa0, ones, lac[0]);
    lac[1] = MFMA16(pa1, ones, lac[1]);
    #pragma unroll
    for (int dhnf=0;dhnf<4;dhnf++){
      bf16x8 vf = *(const bf16x8*)(Vl + (dhnf*16+lo)*64 + vcof);
      o[0][dhnf] = MFMA16(pa0, vf, o[0][dhnf]);
      o[1][dhnf] = MFMA16(pa1, vf, o[1][dhnf]);
    }
    __builtin_amdgcn_s_setprio(0);
    __syncthreads();
    cur ^= 1;
  }
  float* os  = (float*)&Ks[0][0];
  float* lsc = (float*)&Vs[0][0];
  if (wj == 1){
    #pragma unroll
    for (int qnf=0;qnf<2;qnf++){
      #pragma unroll
      for (int dhnf=0;dhnf<4;dhnf++)
        #pragma unroll
        for (int r=0;r<4;r++)
          os[((wi*32 + qnf*16 + 4*hi + r)<<6) + dhnf*16 + lo] = o[qnf][dhnf][r];
      if (lo == 0)
        #pragma unroll
        for (int r=0;r<4;r++)
          lsc[wi*32 + qnf*16 + 4*hi + r] = lac[qnf][r];
    }
  }
  __syncthreads();
  if (wj == 0){
    #pragma unroll
    for (int qnf=0;qnf<2;qnf++)
      #pragma unroll
      for (int r=0;r<4;r++){
        int qloc = wi*32 + qnf*16 + 4*hi + r;
        float lt = lac[qnf][r] + lsc[qloc];
        float rinv = 1.0f / lt;
        #pragma unroll
        for (int dhnf=0;dhnf<4;dhnf++){
          float val = o[qnf][dhnf][r] + os[(qloc<<6) + dhnf*16 + lo];
          O[(size_t)(b*T + qb*64 + qloc)*D + h*64 + dhnf*16 + lo] = f2bf_fast(val * rinv);
        }
      }
  }
}

extern "C" void kernel_launch(void* const* d_in, const int* in_sizes, int n_in,
                              void* d_out, int out_size, void* d_ws, size_t ws_size,
                              hipStream_t stream) {
  const int B=2, T=2048, D=1024;
  const int M = B*T;
  const float* query = (const float*)d_in[0];
  const float* key   = (const float*)d_in[1];
  const float* value = (const float*)d_in[2];
  const float* Wq = (const float*)d_in[3];  const float* bq = (const float*)d_in[4];
  const float* Wk = (const float*)d_in[5];  const float* bk = (const float*)d_in[6];
  const float* Wv = (const float*)d_in[7];  const float* bv = (const float*)d_in[8];
  const float* Wo = (const float*)d_in[9];  const float* bo = (const float*)d_in[10];
  float* out = (float*)d_out;

  char* ws = (char*)d_ws;
  const size_t MB = 1024*1024;
  u16* xq  = (u16*)(ws + 0*MB);
  u16* xk  = (u16*)(ws + 8*MB);
  u16* xv  = (u16*)(ws + 16*MB);
  u16* WqT = (u16*)(ws + 24*MB);
  u16* WkT = (u16*)(ws + 26*MB);
  u16* WvT = (u16*)(ws + 28*MB);
  u16* WoT = (u16*)(ws + 30*MB);
  u16* Qp  = (u16*)(ws + 32*MB);
  u16* Kp  = (u16*)(ws + 40*MB);
  u16* Vp  = (u16*)(ws + 48*MB);
  u16* VTp = (u16*)(ws + 56*MB);
  u16* AO  = (u16*)(ws + 64*MB);

  PrepArgs pa;
  pa.x[0]=query; pa.x[1]=key; pa.x[2]=value;
  pa.y[0]=xq; pa.y[1]=xk; pa.y[2]=xv;
  pa.W[0]=Wq; pa.W[1]=Wk; pa.W[2]=Wv; pa.W[3]=Wo;
  pa.Wt[0]=WqT; pa.Wt[1]=WkT; pa.Wt[2]=WvT; pa.Wt[3]=WoT;
  k_prep<<<16384, 256, 0, stream>>>(pa);

  GemmArgs3 ga;
  ga.A[0]=xq; ga.A[1]=xk; ga.A[2]=xv;
  ga.Bt[0]=WqT; ga.Bt[1]=WkT; ga.Bt[2]=WvT;
  ga.bias[0]=bq; ga.bias[1]=bk; ga.bias[2]=bv;
  ga.C[0]=Qp; ga.C[1]=Kp; ga.C[2]=Vp;
  k_gemm3<<<192, 512, 0, stream>>>(ga);

  k_tv<<<dim3(T/32, 2, 32), dim3(32,8), 0, stream>>>(Vp, VTp);
  k_attn<<<dim3(32,32), 256, 0, stream>>>(Qp, Kp, VTp, AO);
  k_gemmO<<<512, 256, 0, stream>>>(AO, WoT, bo, out);
}